// Round 2
// baseline (755.041 us; speedup 1.0000x reference)
//
#include <hip/hip_runtime.h>
#include <hip/hip_bf16.h>

// Problem constants (from reference)
#define M_TOK 256
#define K_DIM 1024
#define N_DIM 2048
#define NE    64
#define TOPKK 8
#define L_ROWS (M_TOK * TOPKK)   // 2048
#define CAP    (L_ROWS / NE)     // 32 rows per expert (balanced routing)
#define BN    128                // N-tile per block (16 tiles/expert)

typedef __bf16 bf16x8 __attribute__((ext_vector_type(8)));
typedef float  f32x4  __attribute__((ext_vector_type(4)));

// ---------------------------------------------------------------------------
// Routing: one wave per expert; ballot-compact the slots (m*TOPK+t) whose
// topk_id == expert into ws[e*CAP .. e*CAP+31]. Order within expert is
// irrelevant for correctness (each slot writes its own output row).
// ---------------------------------------------------------------------------
__global__ void route_kernel(const int* __restrict__ ids, int* __restrict__ slots) {
    int e    = blockIdx.x;
    int lane = threadIdx.x;           // 0..63
    int base = 0;
    for (int c = 0; c < L_ROWS; c += 64) {
        int slot = c + lane;
        bool match = (ids[slot] == e);
        unsigned long long mask = __ballot(match);
        int pos = __popcll(mask & ((1ULL << lane) - 1ULL));
        if (match) slots[e * CAP + base + pos] = slot;
        base += __popcll(mask);
    }
}

// Build a bf16x8 MFMA fragment from two float4s (8 consecutive k-elements).
__device__ inline bf16x8 cvt8(float4 lo, float4 hi) {
    bf16x8 r;
    r[0] = (__bf16)lo.x; r[1] = (__bf16)lo.y; r[2] = (__bf16)lo.z; r[3] = (__bf16)lo.w;
    r[4] = (__bf16)hi.x; r[5] = (__bf16)hi.y; r[6] = (__bf16)hi.z; r[7] = (__bf16)hi.w;
    return r;
}

// ---------------------------------------------------------------------------
// LDS-free grouped GEMM. Block = (expert, 128-col N-tile); 4 waves; wave wv
// owns n-cols [wv*32, wv*32+32) x all 32 expert rows -> 2x2 acc tiles of
// 16x16. Fragments loaded DIRECTLY global->reg in MFMA layout (lane fr = row,
// k = kg*8..kg*8+7 : two float4), converted fp32->bf16 in registers.
// No LDS, no barriers; depth-1 register prefetch keeps 8 float4/lane in
// flight so the compiler can interleave MFMA with loads at vmcnt>0.
// ---------------------------------------------------------------------------
struct Chunk { float4 v[8]; };   // a0(2), a1(2), b0(2), b1(2) for one K=32 step

__device__ inline void load_chunk(Chunk& c, const float* a0, const float* a1,
                                  const float* b0, const float* b1, int k) {
    c.v[0] = *(const float4*)(a0 + k);     c.v[1] = *(const float4*)(a0 + k + 4);
    c.v[2] = *(const float4*)(a1 + k);     c.v[3] = *(const float4*)(a1 + k + 4);
    c.v[4] = *(const float4*)(b0 + k);     c.v[5] = *(const float4*)(b0 + k + 4);
    c.v[6] = *(const float4*)(b1 + k);     c.v[7] = *(const float4*)(b1 + k + 4);
}

__device__ inline void mfma_step(const Chunk& c, f32x4 acc[2][2]) {
    bf16x8 fa0 = cvt8(c.v[0], c.v[1]);
    bf16x8 fa1 = cvt8(c.v[2], c.v[3]);
    bf16x8 fb0 = cvt8(c.v[4], c.v[5]);
    bf16x8 fb1 = cvt8(c.v[6], c.v[7]);
    acc[0][0] = __builtin_amdgcn_mfma_f32_16x16x32_bf16(fa0, fb0, acc[0][0], 0, 0, 0);
    acc[0][1] = __builtin_amdgcn_mfma_f32_16x16x32_bf16(fa0, fb1, acc[0][1], 0, 0, 0);
    acc[1][0] = __builtin_amdgcn_mfma_f32_16x16x32_bf16(fa1, fb0, acc[1][0], 0, 0, 0);
    acc[1][1] = __builtin_amdgcn_mfma_f32_16x16x32_bf16(fa1, fb1, acc[1][1], 0, 0, 0);
}

__global__ __launch_bounds__(256, 4) void moe_gemm(
    const float* __restrict__ A,      // [M_TOK, K]
    const float* __restrict__ B,      // [E, N, K]
    const float* __restrict__ bias,   // [E, N]
    const float* __restrict__ tw,     // [M_TOK, TOPK] flat
    const int*   __restrict__ slots,  // [E, CAP]
    float*       __restrict__ out)    // [L_ROWS, N]
{
    const int e  = blockIdx.x >> 4;          // 2048/128 = 16 tiles per expert
    const int n0 = (blockIdx.x & 15) * BN;

    const int t    = threadIdx.x;
    const int wv   = t >> 6;       // wave id 0..3
    const int lane = t & 63;
    const int fr   = lane & 15;    // fragment row index (m for A, n for B)
    const int kg   = lane >> 4;    // k-group 0..3 -> k base = kg*8

    // A gather rows (token = slot >> 3 since TOPK=8)
    const int slot0 = slots[e * CAP + fr];
    const int slot1 = slots[e * CAP + fr + 16];
    const float* a0p = A + (size_t)(slot0 >> 3) * K_DIM + kg * 8;
    const float* a1p = A + (size_t)(slot1 >> 3) * K_DIM + kg * 8;

    // B rows
    const int nr = n0 + wv * 32 + fr;
    const float* b0p = B + ((size_t)e * N_DIM + nr) * K_DIM + kg * 8;
    const float* b1p = b0p + (size_t)16 * K_DIM;

    f32x4 acc[2][2] = {{{0.f,0.f,0.f,0.f},{0.f,0.f,0.f,0.f}},
                       {{0.f,0.f,0.f,0.f},{0.f,0.f,0.f,0.f}}};

    Chunk cur, nxt;
    load_chunk(cur, a0p, a1p, b0p, b1p, 0);

    #pragma unroll 2
    for (int k = 32; k < K_DIM; k += 32) {
        load_chunk(nxt, a0p, a1p, b0p, b1p, k);
        mfma_step(cur, acc);
        #pragma unroll
        for (int i = 0; i < 8; i++) cur.v[i] = nxt.v[i];
    }
    mfma_step(cur, acc);

    // ---- epilogue: (acc + bias[e][n]) * tw[slot] -> out[slot][n] ----
    // C/D layout (16x16x32): col(n) = lane&15, row(m) = (lane>>4)*4 + reg
    const int nl0 = n0 + wv * 32 + fr;
    const float bias0 = bias[(size_t)e * N_DIM + nl0];
    const float bias1 = bias[(size_t)e * N_DIM + nl0 + 16];

    #pragma unroll
    for (int mt = 0; mt < 2; mt++) {
        #pragma unroll
        for (int r = 0; r < 4; r++) {
            const int m    = mt * 16 + kg * 4 + r;
            const int slot = slots[e * CAP + m];
            const float wg = tw[slot];
            out[(size_t)slot * N_DIM + nl0]      = (acc[mt][0][r] + bias0) * wg;
            out[(size_t)slot * N_DIM + nl0 + 16] = (acc[mt][1][r] + bias1) * wg;
        }
    }
}

extern "C" void kernel_launch(void* const* d_in, const int* in_sizes, int n_in,
                              void* d_out, int out_size, void* d_ws, size_t ws_size,
                              hipStream_t stream) {
    const float* A    = (const float*)d_in[0];   // [256,1024]
    const float* B    = (const float*)d_in[1];   // [64,2048,1024]
    const float* bias = (const float*)d_in[2];   // [64,2048]
    const float* tw   = (const float*)d_in[3];   // [256,8]
    const int*   ids  = (const int*)d_in[4];     // [256,8]
    float* out  = (float*)d_out;                 // [256,8,2048]
    int* slots  = (int*)d_ws;                    // E*CAP = 2048 ints

    route_kernel<<<NE, 64, 0, stream>>>(ids, slots);
    moe_gemm<<<NE * 16, 256, 0, stream>>>(A, B, bias, tw, slots, out);
}